// Round 1
// baseline (2966.131 us; speedup 1.0000x reference)
//
#include <hip/hip_runtime.h>

#define N_NODES 100000
#define E_EDGES 1600000
#define D 128
#define ROWS 32   // rows of g per GEMM block; 100000 % 32 == 0? No: 100000/32 = 3125 exactly.

// -------- Phase 1: scatter-aggregate g[dst] += h[src] * norm[src] --------
// 32 threads per edge, each handles 4 consecutive floats (float4 gather,
// 4 fp32 global atomics). Edge indices: 2 edges per wave, src/dst loads
// broadcast-served by L1.
__global__ __launch_bounds__(256) void scatter_kernel(
    const float* __restrict__ h, const float* __restrict__ norm,
    const int* __restrict__ src, const int* __restrict__ dst,
    float* __restrict__ g)
{
    const int idx = blockIdx.x * 256 + threadIdx.x;   // < E*32 = 51.2M, fits int
    const int e = idx >> 5;
    const int c = (idx & 31) << 2;
    const int s = src[e];
    const int d = dst[e];
    const float nv = norm[s];
    const float4 hv = *reinterpret_cast<const float4*>(h + s * D + c);
    float* gp = g + d * D + c;
    atomicAdd(gp + 0, hv.x * nv);
    atomicAdd(gp + 1, hv.y * nv);
    atomicAdd(gp + 2, hv.z * nv);
    atomicAdd(gp + 3, hv.w * nv);
}

// -------- Phase 2: out = leaky_relu((g @ W) * norm + bias), in place --------
// Block = 256 threads, 32 rows. g rows staged in LDS (pad +4 keeps float4
// alignment and gives conflict-free 8-row broadcast reads: bank = (4r+k)%32).
// W streamed from global (64 KB, L2/L1-resident; per-instruction the wave
// touches 8 consecutive 16B chunks = 128B, fully coalesced).
// Thread t: row r = t>>3, cols {(t&7)*4 + 32*j + 0..3 : j=0..3} -> 16 accs.
__global__ __launch_bounds__(256) void gemm_epilogue(
    float* __restrict__ out, const float* __restrict__ Wm,
    const float* __restrict__ bias, const float* __restrict__ norm)
{
    __shared__ float gs[ROWS][D + 4];
    const int t = threadIdx.x;
    const int row0 = blockIdx.x * ROWS;

    // stage 32 rows of g (current contents of out) into LDS, coalesced float4
    #pragma unroll
    for (int p = 0; p < 4; ++p) {
        const int i = p * 256 + t;        // 0..1023 float4 chunks
        const int r = i >> 5;
        const int c = (i & 31) << 2;
        const float4 v = *reinterpret_cast<const float4*>(out + (row0 + r) * D + c);
        *reinterpret_cast<float4*>(&gs[r][c]) = v;
    }
    __syncthreads();

    const int r  = t >> 3;
    const int cb = (t & 7) << 2;

    float4 acc[4];
    #pragma unroll
    for (int j = 0; j < 4; ++j) acc[j] = make_float4(0.f, 0.f, 0.f, 0.f);

    for (int k = 0; k < D; k += 4) {
        const float4 gv = *reinterpret_cast<const float4*>(&gs[r][k]);
        float ga[4] = {gv.x, gv.y, gv.z, gv.w};
        #pragma unroll
        for (int kk = 0; kk < 4; ++kk) {
            const float gk = ga[kk];
            #pragma unroll
            for (int j = 0; j < 4; ++j) {
                const float4 wv = *reinterpret_cast<const float4*>(
                    Wm + (k + kk) * D + j * 32 + cb);
                acc[j].x += gk * wv.x;
                acc[j].y += gk * wv.y;
                acc[j].z += gk * wv.z;
                acc[j].w += gk * wv.w;
            }
        }
    }

    const float nv = norm[row0 + r];
    #pragma unroll
    for (int j = 0; j < 4; ++j) {
        const int c = j * 32 + cb;
        const float4 b = *reinterpret_cast<const float4*>(bias + c);
        float4 v;
        v.x = acc[j].x * nv + b.x;
        v.y = acc[j].y * nv + b.y;
        v.z = acc[j].z * nv + b.z;
        v.w = acc[j].w * nv + b.w;
        v.x = v.x > 0.f ? v.x : 0.2f * v.x;
        v.y = v.y > 0.f ? v.y : 0.2f * v.y;
        v.z = v.z > 0.f ? v.z : 0.2f * v.z;
        v.w = v.w > 0.f ? v.w : 0.2f * v.w;
        *reinterpret_cast<float4*>(out + (row0 + r) * D + c) = v;
    }
}

extern "C" void kernel_launch(void* const* d_in, const int* in_sizes, int n_in,
                              void* d_out, int out_size, void* d_ws, size_t ws_size,
                              hipStream_t stream) {
    const float* h    = (const float*)d_in[0];
    const float* norm = (const float*)d_in[1];
    const float* Wm   = (const float*)d_in[2];
    const float* bias = (const float*)d_in[3];
    const int*   src  = (const int*)d_in[4];
    const int*   dst  = (const int*)d_in[5];
    float* out = (float*)d_out;

    // d_out doubles as the aggregation buffer g; zero it first (re-poisoned
    // to 0xAA before every timed call, so this must run every launch).
    hipMemsetAsync(out, 0, (size_t)N_NODES * D * sizeof(float), stream);

    // E*32 threads total = 51,200,000 = 200,000 blocks of 256 exactly
    scatter_kernel<<<(E_EDGES * 32) / 256, 256, 0, stream>>>(h, norm, src, dst, out);

    // 100000 / 32 = 3125 blocks exactly
    gemm_epilogue<<<N_NODES / ROWS, 256, 0, stream>>>(out, Wm, bias, norm);
}

// Round 2
// 595.603 us; speedup vs baseline: 4.9800x; 4.9800x over previous
//
#include <hip/hip_runtime.h>

#define N_NODES 100000
#define E_EDGES 1600000
#define D 128
#define ROWS 32
#define SCAN_B 512                      // items per scan block
#define SCAN_NBLK ((N_NODES + SCAN_B - 1) / SCAN_B)   // 196

// ---- workspace layout (ints) ----
// counts : [0, N)
// off    : [N, 2N]          (N+1 entries)
// pos    : [2N+1, 3N+1)
// bsums  : [3N+1, 3N+1+256)
// boff   : [3N+257, ...)
// esrc   : [3N+513, +E)
#define WS_COUNTS 0
#define WS_OFF    (N_NODES)
#define WS_POS    (2 * N_NODES + 1)
#define WS_BSUMS  (3 * N_NODES + 1)
#define WS_BOFF   (3 * N_NODES + 257)
#define WS_ESRC   (3 * N_NODES + 513)

// -------- 1: histogram of dst --------
__global__ __launch_bounds__(256) void hist_kernel(const int* __restrict__ dst,
                                                   int* __restrict__ counts) {
    const int e = blockIdx.x * 256 + threadIdx.x;   // grid sized exactly E
    atomicAdd(&counts[dst[e]], 1);
}

// -------- 2a: per-block exclusive scan (512 items), writes local scans + block sums
__global__ __launch_bounds__(SCAN_B) void scan_local(const int* __restrict__ counts,
                                                     int* __restrict__ off,
                                                     int* __restrict__ bsums) {
    __shared__ int buf[2][SCAN_B];
    const int t = threadIdx.x;
    const int i = blockIdx.x * SCAN_B + t;
    const int v = (i < N_NODES) ? counts[i] : 0;
    int pi = 0;
    buf[0][t] = v;
    __syncthreads();
    #pragma unroll
    for (int o = 1; o < SCAN_B; o <<= 1) {
        const int nv = buf[pi][t] + (t >= o ? buf[pi][t - o] : 0);
        buf[1 - pi][t] = nv;
        pi = 1 - pi;
        __syncthreads();
    }
    const int incl = buf[pi][t];
    if (i < N_NODES) off[i] = incl - v;         // exclusive local
    if (t == SCAN_B - 1) bsums[blockIdx.x] = incl;
}

// -------- 2b: scan the 196 block sums (single block of 256) --------
__global__ __launch_bounds__(256) void scan_sums(const int* __restrict__ bsums,
                                                 int* __restrict__ boff) {
    __shared__ int buf[2][256];
    const int t = threadIdx.x;
    const int v = (t < SCAN_NBLK) ? bsums[t] : 0;
    int pi = 0;
    buf[0][t] = v;
    __syncthreads();
    #pragma unroll
    for (int o = 1; o < 256; o <<= 1) {
        const int nv = buf[pi][t] + (t >= o ? buf[pi][t - o] : 0);
        buf[1 - pi][t] = nv;
        pi = 1 - pi;
        __syncthreads();
    }
    if (t < SCAN_NBLK) boff[t] = buf[pi][t] - v;   // exclusive
}

// -------- 2c: add block offsets; replicate into pos[]; off[N]=E --------
__global__ __launch_bounds__(SCAN_B) void scan_add(int* __restrict__ off,
                                                   int* __restrict__ pos,
                                                   const int* __restrict__ boff) {
    const int t = threadIdx.x;
    const int i = blockIdx.x * SCAN_B + t;
    if (i < N_NODES) {
        const int o = off[i] + boff[blockIdx.x];
        off[i] = o;
        pos[i] = o;
    }
    if (blockIdx.x == 0 && t == 0) off[N_NODES] = E_EDGES;
}

// -------- 3: bucket edges by dst --------
__global__ __launch_bounds__(256) void bucket_kernel(const int* __restrict__ src,
                                                     const int* __restrict__ dst,
                                                     int* __restrict__ pos,
                                                     int* __restrict__ esrc) {
    const int e = blockIdx.x * 256 + threadIdx.x;   // grid sized exactly E
    const int p = atomicAdd(&pos[dst[e]], 1);
    esrc[p] = src[e];
}

// -------- 4: pull-gather g[n] = sum_{e: dst=n} h[src]*norm[src] --------
// 32 threads per node (float4 cols), 8 nodes per block. No atomics.
__global__ __launch_bounds__(256) void gather_kernel(const float* __restrict__ h,
                                                     const float* __restrict__ norm,
                                                     const int* __restrict__ off,
                                                     const int* __restrict__ esrc,
                                                     float* __restrict__ g) {
    const int t = threadIdx.x;
    const int node = blockIdx.x * 8 + (t >> 5);     // grid*8 == N exactly
    const int c = (t & 31) << 2;
    const int beg = off[node];
    const int end = off[node + 1];
    float4 acc = make_float4(0.f, 0.f, 0.f, 0.f);
    for (int i = beg; i < end; ++i) {
        const int s = esrc[i];
        const float nv = norm[s];
        const float4 hv = *reinterpret_cast<const float4*>(h + s * D + c);
        acc.x += hv.x * nv;
        acc.y += hv.y * nv;
        acc.z += hv.z * nv;
        acc.w += hv.w * nv;
    }
    *reinterpret_cast<float4*>(g + node * D + c) = acc;
}

// -------- 5: out = leaky_relu((g @ W) * norm + bias), in place --------
__global__ __launch_bounds__(256) void gemm_epilogue(
    float* __restrict__ out, const float* __restrict__ Wm,
    const float* __restrict__ bias, const float* __restrict__ norm)
{
    __shared__ float gs[ROWS][D + 4];
    const int t = threadIdx.x;
    const int row0 = blockIdx.x * ROWS;

    #pragma unroll
    for (int p = 0; p < 4; ++p) {
        const int i = p * 256 + t;
        const int r = i >> 5;
        const int c = (i & 31) << 2;
        const float4 v = *reinterpret_cast<const float4*>(out + (row0 + r) * D + c);
        *reinterpret_cast<float4*>(&gs[r][c]) = v;
    }
    __syncthreads();

    const int r  = t >> 3;
    const int cb = (t & 7) << 2;

    float4 acc[4];
    #pragma unroll
    for (int j = 0; j < 4; ++j) acc[j] = make_float4(0.f, 0.f, 0.f, 0.f);

    for (int k = 0; k < D; k += 4) {
        const float4 gv = *reinterpret_cast<const float4*>(&gs[r][k]);
        float ga[4] = {gv.x, gv.y, gv.z, gv.w};
        #pragma unroll
        for (int kk = 0; kk < 4; ++kk) {
            const float gk = ga[kk];
            #pragma unroll
            for (int j = 0; j < 4; ++j) {
                const float4 wv = *reinterpret_cast<const float4*>(
                    Wm + (k + kk) * D + j * 32 + cb);
                acc[j].x += gk * wv.x;
                acc[j].y += gk * wv.y;
                acc[j].z += gk * wv.z;
                acc[j].w += gk * wv.w;
            }
        }
    }

    const float nv = norm[row0 + r];
    #pragma unroll
    for (int j = 0; j < 4; ++j) {
        const int c = j * 32 + cb;
        const float4 b = *reinterpret_cast<const float4*>(bias + c);
        float4 v;
        v.x = acc[j].x * nv + b.x;
        v.y = acc[j].y * nv + b.y;
        v.z = acc[j].z * nv + b.z;
        v.w = acc[j].w * nv + b.w;
        v.x = v.x > 0.f ? v.x : 0.2f * v.x;
        v.y = v.y > 0.f ? v.y : 0.2f * v.y;
        v.z = v.z > 0.f ? v.z : 0.2f * v.z;
        v.w = v.w > 0.f ? v.w : 0.2f * v.w;
        *reinterpret_cast<float4*>(out + (row0 + r) * D + c) = v;
    }
}

extern "C" void kernel_launch(void* const* d_in, const int* in_sizes, int n_in,
                              void* d_out, int out_size, void* d_ws, size_t ws_size,
                              hipStream_t stream) {
    const float* h    = (const float*)d_in[0];
    const float* norm = (const float*)d_in[1];
    const float* Wm   = (const float*)d_in[2];
    const float* bias = (const float*)d_in[3];
    const int*   src  = (const int*)d_in[4];
    const int*   dst  = (const int*)d_in[5];
    float* out = (float*)d_out;
    int* ws = (int*)d_ws;

    int* counts = ws + WS_COUNTS;
    int* off    = ws + WS_OFF;
    int* pos    = ws + WS_POS;
    int* bsums  = ws + WS_BSUMS;
    int* boff   = ws + WS_BOFF;
    int* esrc   = ws + WS_ESRC;

    // zero only the histogram counters (ws is re-poisoned to 0xAA each call)
    hipMemsetAsync(counts, 0, N_NODES * sizeof(int), stream);

    hist_kernel <<<E_EDGES / 256, 256, 0, stream>>>(dst, counts);
    scan_local  <<<SCAN_NBLK, SCAN_B, 0, stream>>>(counts, off, bsums);
    scan_sums   <<<1, 256, 0, stream>>>(bsums, boff);
    scan_add    <<<SCAN_NBLK, SCAN_B, 0, stream>>>(off, pos, boff);
    bucket_kernel<<<E_EDGES / 256, 256, 0, stream>>>(src, dst, pos, esrc);
    gather_kernel<<<N_NODES / 8, 256, 0, stream>>>(h, norm, off, esrc, out);
    gemm_epilogue<<<N_NODES / ROWS, 256, 0, stream>>>(out, Wm, bias, norm);
}

// Round 3
// 476.062 us; speedup vs baseline: 6.2306x; 1.2511x over previous
//
#include <hip/hip_runtime.h>

#define N_NODES 100000
#define E_EDGES 1600000
#define D 128
#define SCAN_B 512
#define SCAN_NBLK ((N_NODES + SCAN_B - 1) / SCAN_B)   // 196

// GEMM tiling
#define GROWS 64            // g-rows per block
#define KCH 32              // k-chunk staged in LDS

// ---- workspace layout (ints) ----
#define WS_COUNTS 0
#define WS_OFF    (N_NODES)
#define WS_POS    (2 * N_NODES + 1)
#define WS_BSUMS  (3 * N_NODES + 1)
#define WS_BOFF   (3 * N_NODES + 257)
#define WS_ESRC   (3 * N_NODES + 513)

// -------- 1: histogram of dst --------
__global__ __launch_bounds__(256) void hist_kernel(const int* __restrict__ dst,
                                                   int* __restrict__ counts) {
    const int e = blockIdx.x * 256 + threadIdx.x;
    atomicAdd(&counts[dst[e]], 1);
}

// -------- 2a: per-block exclusive scan --------
__global__ __launch_bounds__(SCAN_B) void scan_local(const int* __restrict__ counts,
                                                     int* __restrict__ off,
                                                     int* __restrict__ bsums) {
    __shared__ int buf[2][SCAN_B];
    const int t = threadIdx.x;
    const int i = blockIdx.x * SCAN_B + t;
    const int v = (i < N_NODES) ? counts[i] : 0;
    int pi = 0;
    buf[0][t] = v;
    __syncthreads();
    #pragma unroll
    for (int o = 1; o < SCAN_B; o <<= 1) {
        const int nv = buf[pi][t] + (t >= o ? buf[pi][t - o] : 0);
        buf[1 - pi][t] = nv;
        pi = 1 - pi;
        __syncthreads();
    }
    const int incl = buf[pi][t];
    if (i < N_NODES) off[i] = incl - v;
    if (t == SCAN_B - 1) bsums[blockIdx.x] = incl;
}

// -------- 2b: scan block sums --------
__global__ __launch_bounds__(256) void scan_sums(const int* __restrict__ bsums,
                                                 int* __restrict__ boff) {
    __shared__ int buf[2][256];
    const int t = threadIdx.x;
    const int v = (t < SCAN_NBLK) ? bsums[t] : 0;
    int pi = 0;
    buf[0][t] = v;
    __syncthreads();
    #pragma unroll
    for (int o = 1; o < 256; o <<= 1) {
        const int nv = buf[pi][t] + (t >= o ? buf[pi][t - o] : 0);
        buf[1 - pi][t] = nv;
        pi = 1 - pi;
        __syncthreads();
    }
    if (t < SCAN_NBLK) boff[t] = buf[pi][t] - v;
}

// -------- 2c: add block offsets --------
__global__ __launch_bounds__(SCAN_B) void scan_add(int* __restrict__ off,
                                                   int* __restrict__ pos,
                                                   const int* __restrict__ boff) {
    const int t = threadIdx.x;
    const int i = blockIdx.x * SCAN_B + t;
    if (i < N_NODES) {
        const int o = off[i] + boff[blockIdx.x];
        off[i] = o;
        pos[i] = o;
    }
    if (blockIdx.x == 0 && t == 0) off[N_NODES] = E_EDGES;
}

// -------- 3: bucket edges by dst --------
__global__ __launch_bounds__(256) void bucket_kernel(const int* __restrict__ src,
                                                     const int* __restrict__ dst,
                                                     int* __restrict__ pos,
                                                     int* __restrict__ esrc) {
    const int e = blockIdx.x * 256 + threadIdx.x;
    const int p = atomicAdd(&pos[dst[e]], 1);
    esrc[p] = src[e];
}

// -------- 4: pull-gather, no atomics --------
__global__ __launch_bounds__(256) void gather_kernel(const float* __restrict__ h,
                                                     const float* __restrict__ norm,
                                                     const int* __restrict__ off,
                                                     const int* __restrict__ esrc,
                                                     float* __restrict__ g) {
    const int t = threadIdx.x;
    const int node = blockIdx.x * 8 + (t >> 5);
    const int c = (t & 31) << 2;
    const int beg = off[node];
    const int end = off[node + 1];
    float4 acc = make_float4(0.f, 0.f, 0.f, 0.f);
    for (int i = beg; i < end; ++i) {
        const int s = esrc[i];
        const float nv = norm[s];
        const float4 hv = *reinterpret_cast<const float4*>(h + s * D + c);
        acc.x += hv.x * nv;
        acc.y += hv.y * nv;
        acc.z += hv.z * nv;
        acc.w += hv.w * nv;
    }
    *reinterpret_cast<float4*>(g + node * D + c) = acc;
}

// -------- 5: out = leaky_relu((g @ W) * norm + bias), in place --------
// 64 rows/block; W staged in LDS in 32-k chunks. Thread t: rows
// (t>>5)*8 + {0..7}, cols (t&31)*4 + {0..3} -> 8 float4 accumulators.
// LDS: gs 64x132 (33.8 KB) + Wlds 32x128 (16 KB) = 49.8 KB -> 3 blocks/CU.
__global__ __launch_bounds__(256) void gemm_epilogue(
    float* __restrict__ out, const float* __restrict__ Wm,
    const float* __restrict__ bias, const float* __restrict__ norm)
{
    __shared__ float gs[GROWS][D + 4];
    __shared__ float Wlds[KCH][D];
    const int t = threadIdx.x;
    const int row0 = blockIdx.x * GROWS;

    // stage 64 rows of g (clamp tail rows; stores guarded later)
    #pragma unroll
    for (int p = 0; p < 8; ++p) {
        const int i = p * 256 + t;            // 0..2047 float4 chunks
        const int r = i >> 5;
        const int c = (i & 31) << 2;
        int gr = row0 + r;
        if (gr >= N_NODES) gr = N_NODES - 1;
        const float4 v = *reinterpret_cast<const float4*>(out + gr * D + c);
        *reinterpret_cast<float4*>(&gs[r][c]) = v;
    }

    const int rg = (t >> 5) * 8;              // first of 8 rows
    const int cb = (t & 31) << 2;             // 4 cols

    float4 acc[8];
    #pragma unroll
    for (int i = 0; i < 8; ++i) acc[i] = make_float4(0.f, 0.f, 0.f, 0.f);

    for (int kc = 0; kc < D; kc += KCH) {
        __syncthreads();                       // protect Wlds reuse + gs on first iter
        // stage W[kc..kc+31][0..127] : 1024 float4s, 4 per thread
        #pragma unroll
        for (int p = 0; p < 4; ++p) {
            const int i = p * 256 + t;
            const int kk = i >> 5;
            const int c = (i & 31) << 2;
            const float4 v = *reinterpret_cast<const float4*>(Wm + (kc + kk) * D + c);
            *reinterpret_cast<float4*>(&Wlds[kk][c]) = v;
        }
        __syncthreads();

        #pragma unroll
        for (int k4 = 0; k4 < KCH; k4 += 4) {
            float4 wv[4];
            #pragma unroll
            for (int kk = 0; kk < 4; ++kk)
                wv[kk] = *reinterpret_cast<const float4*>(&Wlds[k4 + kk][cb]);
            #pragma unroll
            for (int i = 0; i < 8; ++i) {
                const float4 gv = *reinterpret_cast<const float4*>(&gs[rg + i][kc + k4]);
                acc[i].x += gv.x * wv[0].x; acc[i].y += gv.x * wv[0].y;
                acc[i].z += gv.x * wv[0].z; acc[i].w += gv.x * wv[0].w;
                acc[i].x += gv.y * wv[1].x; acc[i].y += gv.y * wv[1].y;
                acc[i].z += gv.y * wv[1].z; acc[i].w += gv.y * wv[1].w;
                acc[i].x += gv.z * wv[2].x; acc[i].y += gv.z * wv[2].y;
                acc[i].z += gv.z * wv[2].z; acc[i].w += gv.z * wv[2].w;
                acc[i].x += gv.w * wv[3].x; acc[i].y += gv.w * wv[3].y;
                acc[i].z += gv.w * wv[3].z; acc[i].w += gv.w * wv[3].w;
            }
        }
    }

    const float4 b = *reinterpret_cast<const float4*>(bias + cb);
    #pragma unroll
    for (int i = 0; i < 8; ++i) {
        const int gr = row0 + rg + i;
        if (gr < N_NODES) {
            const float nv = norm[gr];
            float4 v;
            v.x = acc[i].x * nv + b.x;
            v.y = acc[i].y * nv + b.y;
            v.z = acc[i].z * nv + b.z;
            v.w = acc[i].w * nv + b.w;
            v.x = v.x > 0.f ? v.x : 0.2f * v.x;
            v.y = v.y > 0.f ? v.y : 0.2f * v.y;
            v.z = v.z > 0.f ? v.z : 0.2f * v.z;
            v.w = v.w > 0.f ? v.w : 0.2f * v.w;
            *reinterpret_cast<float4*>(out + gr * D + cb) = v;
        }
    }
}

extern "C" void kernel_launch(void* const* d_in, const int* in_sizes, int n_in,
                              void* d_out, int out_size, void* d_ws, size_t ws_size,
                              hipStream_t stream) {
    const float* h    = (const float*)d_in[0];
    const float* norm = (const float*)d_in[1];
    const float* Wm   = (const float*)d_in[2];
    const float* bias = (const float*)d_in[3];
    const int*   src  = (const int*)d_in[4];
    const int*   dst  = (const int*)d_in[5];
    float* out = (float*)d_out;
    int* ws = (int*)d_ws;

    int* counts = ws + WS_COUNTS;
    int* off    = ws + WS_OFF;
    int* pos    = ws + WS_POS;
    int* bsums  = ws + WS_BSUMS;
    int* boff   = ws + WS_BOFF;
    int* esrc   = ws + WS_ESRC;

    hipMemsetAsync(counts, 0, N_NODES * sizeof(int), stream);

    hist_kernel <<<E_EDGES / 256, 256, 0, stream>>>(dst, counts);
    scan_local  <<<SCAN_NBLK, SCAN_B, 0, stream>>>(counts, off, bsums);
    scan_sums   <<<1, 256, 0, stream>>>(bsums, boff);
    scan_add    <<<SCAN_NBLK, SCAN_B, 0, stream>>>(off, pos, boff);
    bucket_kernel<<<E_EDGES / 256, 256, 0, stream>>>(src, dst, pos, esrc);
    gather_kernel<<<N_NODES / 8, 256, 0, stream>>>(h, norm, off, esrc, out);
    gemm_epilogue<<<(N_NODES + GROWS - 1) / GROWS, 256, 0, stream>>>(out, Wm, bias, norm);
}